// Round 1
// baseline (127.267 us; speedup 1.0000x reference)
//
#include <hip/hip_runtime.h>
#include <math.h>

// Problem constants (reference: B=4, N=M=8192, D=3, fp32)
#define BQ      4
#define NPTS    8192
#define WG      256
#define CHUNK   1024              // m-points staged in LDS per block
#define UNROLL_A 4                // a-points per thread (registers)
#define ABLK    (WG * UNROLL_A)   // 1024 a-points per block

// For each a-point, min squared distance over one m-chunk of b-points.
// blockIdx.x: a-chunk (8), blockIdx.y: m-chunk (8), blockIdx.z: batch*2+dir (8)
__global__ __launch_bounds__(WG) void chamfer_min_kernel(
    const float* __restrict__ yhat, const float* __restrict__ y,
    unsigned* __restrict__ minsq /* [2*BQ][NPTS] float bits */) {
  const int bz  = blockIdx.z;
  const int b   = bz >> 1;
  const int dir = bz & 1;
  const float* A  = (dir ? y    : yhat) + (size_t)b * NPTS * 3;
  const float* Bp = (dir ? yhat : y   ) + (size_t)b * NPTS * 3;
  unsigned* outm  = minsq + (size_t)bz * NPTS;

  __shared__ float xs[CHUNK], ys[CHUNK], zs[CHUNK];
  const int m0 = blockIdx.y * CHUNK;
  for (int i = threadIdx.x; i < CHUNK; i += WG) {
    const float* p = Bp + (size_t)(m0 + i) * 3;
    xs[i] = p[0]; ys[i] = p[1]; zs[i] = p[2];
  }

  const int nbase = blockIdx.x * ABLK + threadIdx.x;
  float ax[UNROLL_A], ay[UNROLL_A], az[UNROLL_A], mn[UNROLL_A];
#pragma unroll
  for (int k = 0; k < UNROLL_A; ++k) {
    const float* p = A + (size_t)(nbase + k * WG) * 3;
    ax[k] = p[0]; ay[k] = p[1]; az[k] = p[2];
    mn[k] = 3.0e38f;
  }
  __syncthreads();

#pragma unroll 4
  for (int m = 0; m < CHUNK; ++m) {
    const float bx = xs[m], by = ys[m], bzv = zs[m];
#pragma unroll
    for (int k = 0; k < UNROLL_A; ++k) {
      const float dx = ax[k] - bx;
      const float dy = ay[k] - by;
      const float dz = az[k] - bzv;
      float d2 = dx * dx;
      d2 = fmaf(dy, dy, d2);
      d2 = fmaf(dz, dz, d2);
      mn[k] = fminf(mn[k], d2);
    }
  }

#pragma unroll
  for (int k = 0; k < UNROLL_A; ++k)
    atomicMin(&outm[nbase + k * WG], __float_as_uint(mn[k]));
}

// Sum all 2*B*N per-point mins into one float accumulator.
__global__ __launch_bounds__(256) void chamfer_reduce_kernel(
    const unsigned* __restrict__ minsq, float* __restrict__ acc) {
  const int count = 2 * BQ * NPTS;
  float s = 0.f;
  for (int i = blockIdx.x * blockDim.x + threadIdx.x; i < count;
       i += gridDim.x * blockDim.x)
    s += __uint_as_float(minsq[i]);
#pragma unroll
  for (int off = 32; off > 0; off >>= 1)
    s += __shfl_down(s, off, 64);
  __shared__ float part[4];
  const int wave = threadIdx.x >> 6, lane = threadIdx.x & 63;
  if (lane == 0) part[wave] = s;
  __syncthreads();
  if (threadIdx.x == 0) {
    atomicAdd(acc, part[0] + part[1] + part[2] + part[3]);
  }
}

// loss = acc / (B*N); out = sqrt(0.5 * loss) = sqrt(acc / (2*B*N))
__global__ void chamfer_final_kernel(const float* __restrict__ acc,
                                     float* __restrict__ out) {
  out[0] = sqrtf(acc[0] * (1.0f / (2.0f * BQ * NPTS)));
}

extern "C" void kernel_launch(void* const* d_in, const int* in_sizes, int n_in,
                              void* d_out, int out_size, void* d_ws, size_t ws_size,
                              hipStream_t stream) {
  const float* yhat = (const float*)d_in[0];
  const float* y    = (const float*)d_in[1];
  unsigned* minsq = (unsigned*)d_ws;
  float* acc = (float*)((char*)d_ws + (size_t)2 * BQ * NPTS * sizeof(unsigned));

  // ws is re-poisoned to 0xAA before every timed launch — re-init every call.
  hipMemsetAsync(minsq, 0x7F, (size_t)2 * BQ * NPTS * sizeof(unsigned), stream);
  hipMemsetAsync(acc, 0, sizeof(float), stream);

  dim3 grid(NPTS / ABLK, NPTS / CHUNK, 2 * BQ);
  chamfer_min_kernel<<<grid, WG, 0, stream>>>(yhat, y, minsq);
  chamfer_reduce_kernel<<<64, 256, 0, stream>>>(minsq, acc);
  chamfer_final_kernel<<<1, 1, 0, stream>>>(acc, (float*)d_out);
}

// Round 2
// 112.240 us; speedup vs baseline: 1.1339x; 1.1339x over previous
//
#include <hip/hip_runtime.h>
#include <math.h>

// Problem constants (reference: B=4, N=M=8192, D=3, fp32)
#define BQ     4
#define NPTS   8192
#define WG     256
#define CHUNK  1024               // m-points staged in LDS per block
#define UA     4                  // a-points per thread (registers)
#define ABLK   (WG * UA)          // 1024 a-points per block
#define NCH    (NPTS / CHUNK)     // 8 m-chunks
#define TOTALA (2 * BQ * NPTS)    // 65536 a-points across batch*dir

// Per (a-chunk, m-chunk, batch*dir): min over the m-chunk of
//   d^2 = ||a||^2 + (||b||^2 - 2 a.b)
// using pre-transformed b' = (-2bx, -2by, -2bz, ||b||^2) so the inner
// update is 3 fma + shared min (v_min3 via paired m-points).
__global__ __launch_bounds__(WG) void chamfer_min_kernel(
    const float* __restrict__ yhat, const float* __restrict__ y,
    unsigned* __restrict__ part, int atomicPath) {
  const int bz = blockIdx.z, b = bz >> 1, dir = bz & 1;
  const float* A  = (dir ? y    : yhat) + (size_t)b * NPTS * 3;
  const float* Bp = (dir ? yhat : y   ) + (size_t)b * NPTS * 3;

  __shared__ float4 bs[CHUNK];
  const int m0 = blockIdx.y * CHUNK;
  for (int i = threadIdx.x; i < CHUNK; i += WG) {
    const float* p = Bp + (size_t)(m0 + i) * 3;
    const float x = p[0], yv = p[1], z = p[2];
    bs[i] = make_float4(-2.f * x, -2.f * yv, -2.f * z,
                        fmaf(x, x, fmaf(yv, yv, z * z)));
  }

  const int nbase = blockIdx.x * ABLK + threadIdx.x;
  float ax[UA], ay[UA], az[UA], mn[UA];
#pragma unroll
  for (int k = 0; k < UA; ++k) {
    const float* p = A + (size_t)(nbase + k * WG) * 3;
    ax[k] = p[0]; ay[k] = p[1]; az[k] = p[2];
    mn[k] = 3.0e38f;
  }
  __syncthreads();

#pragma unroll 2
  for (int m = 0; m < CHUNK; m += 2) {
    const float4 b0 = bs[m], b1 = bs[m + 1];
#pragma unroll
    for (int k = 0; k < UA; ++k) {
      const float t0 = fmaf(ax[k], b0.x, fmaf(ay[k], b0.y, fmaf(az[k], b0.z, b0.w)));
      const float t1 = fmaf(ax[k], b1.x, fmaf(ay[k], b1.y, fmaf(az[k], b1.z, b1.w)));
      mn[k] = fminf(mn[k], fminf(t0, t1));  // fuses to v_min3_f32
    }
  }

  const int base = bz * NPTS + blockIdx.x * ABLK + threadIdx.x;
  if (atomicPath) {
#pragma unroll
    for (int k = 0; k < UA; ++k) {
      const float sq = fmaf(ax[k], ax[k], fmaf(ay[k], ay[k], az[k] * az[k]));
      const float d2 = fmaxf(sq + mn[k], 0.f);
      atomicMin(&part[base + k * WG], __float_as_uint(d2));
    }
  } else {
    unsigned* outp = part + (size_t)blockIdx.y * TOTALA;
#pragma unroll
    for (int k = 0; k < UA; ++k) {
      const float sq = fmaf(ax[k], ax[k], fmaf(ay[k], ay[k], az[k] * az[k]));
      const float d2 = fmaxf(sq + mn[k], 0.f);
      outp[base + k * WG] = __float_as_uint(d2);
    }
  }
}

// min across m-chunks, then sum-reduce to one partial per block.
__global__ __launch_bounds__(256) void chamfer_reduce_kernel(
    const unsigned* __restrict__ part, float* __restrict__ bsums, int nch) {
  const int gid = blockIdx.x * 256 + threadIdx.x;  // 64 blocks -> 0..16383
  float s = 0.f;
  for (int rep = 0; rep < TOTALA / (64 * 256); ++rep) {
    const int j = rep * 16384 + gid;
    float mv = __uint_as_float(part[j]);
    for (int mc = 1; mc < nch; ++mc)
      mv = fminf(mv, __uint_as_float(part[(size_t)mc * TOTALA + j]));
    s += mv;
  }
#pragma unroll
  for (int off = 32; off > 0; off >>= 1) s += __shfl_down(s, off, 64);
  __shared__ float p4[4];
  const int wave = threadIdx.x >> 6, lane = threadIdx.x & 63;
  if (lane == 0) p4[wave] = s;
  __syncthreads();
  if (threadIdx.x == 0) bsums[blockIdx.x] = p4[0] + p4[1] + p4[2] + p4[3];
}

// out = sqrt(0.5 * mean_b(fwd+bwd)) = sqrt(total_sum / 65536)
__global__ void chamfer_final_kernel(const float* __restrict__ bsums,
                                     float* __restrict__ out) {
  float s = bsums[threadIdx.x];  // 64 threads, 64 partials
#pragma unroll
  for (int off = 32; off > 0; off >>= 1) s += __shfl_down(s, off, 64);
  if (threadIdx.x == 0) out[0] = sqrtf(s * (1.0f / (float)TOTALA));
}

extern "C" void kernel_launch(void* const* d_in, const int* in_sizes, int n_in,
                              void* d_out, int out_size, void* d_ws, size_t ws_size,
                              hipStream_t stream) {
  const float* yhat = (const float*)d_in[0];
  const float* y    = (const float*)d_in[1];
  unsigned* part = (unsigned*)d_ws;

  const size_t needFull = (size_t)NCH * TOTALA * sizeof(unsigned) + 64 * sizeof(float);
  const int atomicPath = ws_size < needFull;

  float* bsums;
  if (atomicPath) {
    // init to +big so atomicMin works on float bits (all d2 >= 0)
    hipMemsetAsync(part, 0x7F, (size_t)TOTALA * sizeof(unsigned), stream);
    bsums = (float*)(part + TOTALA);
  } else {
    bsums = (float*)(part + (size_t)NCH * TOTALA);
  }

  dim3 grid(NPTS / ABLK, NCH, 2 * BQ);
  chamfer_min_kernel<<<grid, WG, 0, stream>>>(yhat, y, part, atomicPath);
  chamfer_reduce_kernel<<<64, 256, 0, stream>>>(part, bsums, atomicPath ? 1 : NCH);
  chamfer_final_kernel<<<1, 64, 0, stream>>>(bsums, (float*)d_out);
}